// Round 12
// baseline (578.775 us; speedup 1.0000x reference)
//
#include <hip/hip_runtime.h>
#include <hip/hip_bf16.h>
#include <math.h>

#define BN 4
#define CHN 64
#define HH 256
#define WW 256
#define HWSZ (HH*WW)
#define EPSV 1e-5f
#define CP 72   // LDS channel-dim pad in shorts: 144B row stride -> 16B-aligned b128, balanced banks

typedef __attribute__((ext_vector_type(8)))  short  short8;
typedef __attribute__((ext_vector_type(4)))  short  short4v;
typedef __attribute__((ext_vector_type(16))) float  floatx16;

__device__ __forceinline__ int refl(int i, int n){ if(i<0)i=-i; if(i>=n)i=2*n-2-i; return i; }
__device__ __forceinline__ short f2bf(float f){ __hip_bfloat16 h=__float2bfloat16(f); return __builtin_bit_cast(short,h); }
__device__ __forceinline__ float bf2f(short s){ unsigned u=((unsigned)(unsigned short)s)<<16; return __builtin_bit_cast(float,u); }

// DPP-based add of a cross-lane shifted copy (VALU pipe only, no LDS traffic)
template<int CTRL>
__device__ __forceinline__ float dpp_add(float x){
    int y = __builtin_amdgcn_update_dpp(0, __builtin_bit_cast(int, x), CTRL, 0xF, 0xF, true);
    return x + __builtin_bit_cast(float, y);
}
// Reduce over the 32 "column" lanes of each 32-half.
// After this, lanes 16 (for lanes 0-31) and 48 (for lanes 32-63) hold the half sums.
__device__ __forceinline__ float red_cols(float x){
    x = dpp_add<0xB1>(x);    // quad_perm [1,0,3,2]  : xor 1
    x = dpp_add<0x4E>(x);    // quad_perm [2,3,0,1]  : xor 2
    x = dpp_add<0x124>(x);   // row_ror:4
    x = dpp_add<0x128>(x);   // row_ror:8  -> every lane holds its 16-row sum
    x = dpp_add<0x142>(x);   // row_bcast15 -> rows 1,3 accumulate rows 0,2
    return x;
}

// ---------------- fused guide + conv1x1: K[b,t,y,x] and A = w0*x+b0 (channels-last bf16) ----
// Also zeroes the 24 per-(pac,b) stat completion counters (runs before all pacs).
__global__ void gc_kernel(const float* __restrict__ x, const float* __restrict__ w0,
                          const float* __restrict__ b0, float* __restrict__ Kb,
                          short* __restrict__ A, int* __restrict__ cnt){
    int idx = blockIdx.x * 256 + threadIdx.x;        // BN*HWSZ
    if (blockIdx.x == 0 && threadIdx.x < 32) cnt[threadIdx.x] = 0;
    int b = idx / HWSZ, p = idx - b*HWSZ;
    int y = p / WW, xx = p - y*WW;
    const float* g = x + (size_t)b*HWSZ;
    float gc = g[p];
#pragma unroll
    for (int t = 0; t < 9; ++t) {
        int yy  = refl(y + t/3 - 1, HH);
        int xx2 = refl(xx + t%3 - 1, WW);
        float d = g[yy*WW + xx2] - gc;
        Kb[((size_t)b*9 + t)*HWSZ + p] = __expf(-0.5f*d*d);
    }
    short* Ap = A + ((size_t)b*HWSZ + p)*64;
#pragma unroll
    for (int oc = 0; oc < 8; ++oc) {
        short8 r;
#pragma unroll
        for (int j = 0; j < 8; ++j) {
            int c = oc*8 + j;
            r[j] = f2bf(fmaf(w0[c], gc, b0[c]));
        }
        *(short8*)(Ap + oc*8) = r;
    }
}

// ---------------- pack all 7 weight tensors into 32x32x16 A-fragment order ----------------
// frag = (t*4+cg)*2+oh ; o = oh*32+(lane&31) ; c = cg*16+(lane>>5)*8+j
__global__ void pack_all(const float* w1,const float* w2,const float* w3,const float* w4,
                         const float* w5,const float* w6,const float* w7, short* __restrict__ Ap){
    const float* wsrc[7] = {w1,w2,w3,w4,w5,w6,w7};
    int layer = blockIdx.y;
    int tid = blockIdx.x*256 + threadIdx.x;          // 0..36863
    int j    = tid & 7;
    int lane = (tid >> 3) & 63;
    int frag = tid >> 9;                             // 0..71
    int oh = frag & 1, cg = (frag >> 1) & 3, t = frag >> 3;
    int o = oh*32 + (lane & 31);
    int c = cg*16 + (lane >> 5)*8 + j;
    Ap[(size_t)layer*36864 + tid] = f2bf(wsrc[layer][(o*CHN + c)*9 + t]);
}

// ---------------- PAC conv, implicit GEMM on mfma_32x32x16_bf16 ----------------
// Block: 64 o x (32 px x 2 rows), 256 threads (R2-PROVEN config: __launch_bounds__(256,4),
// 56 VGPR, zero scratch). HW VGPR tiers step at 64/128/256 (R8/R9: any launch-bounds
// >4 waves/EU forces the <=64 tier and spills this body -- do NOT raise).
// Wave(oh=w&1, wrow=w>>1): 32 o x 32 px.
// h halo (4 rows x 34 px x 64 c, bf16 channels-last) staged to LDS ONCE; taps read
// shifted windows. K applied per tap on the C-tile (col=lane&31 = pixel):
//   acc += K[t,px] * (W_t x h_shift)  -- B-frags are RAW h, no per-element modulate.
// NORM=1:  staging applies (v-mean)*rstd,relu from stats of hin (fuses applyrelu).
// FUSEA=1: staging computes h := relu(hin + (cin-mean)*rstd) -- residual addnorm fused
//          (stats are of cin). WB=1 writes the block's own 2 interior rows of h back to
//          aout (each element written by exactly one block; readers in later dispatches).
// STATS=1: epilogue accumulates per-(b,channel) sum/sumsq of fp32 outputs (bias incl.,
//          pre-relu) via DPP column reduce; block partials stored as one 512B record
//          via AGENT-SCOPE atomic stores (L2-write-through, no fence/L2-invalidate);
//          the 1024th block per b (device counter) reduces the 1024 records via
//          agent-scope atomic loads (L2-bypass, no stale-line hazard) and writes st --
//          the separate reduce_stats dispatch is gone. Kernel-boundary release makes
//          st visible to the next dispatch (same guarantee the old path relied on).
template<int NORM, int FUSEA, int WB, int HASK, int FINAL, int STATS>
__global__ void __launch_bounds__(256, 4) pac_mfma(
    const short* __restrict__ hin, const short* __restrict__ cin,
    const float* __restrict__ Kb,
    const short* __restrict__ Ap, const float* __restrict__ bias,
    const float* __restrict__ stin, short* __restrict__ outb, float* __restrict__ outf,
    short* __restrict__ aout, float* __restrict__ stpart, float* __restrict__ stfin,
    int* __restrict__ cnt)
{
    __shared__ short lds[4*34*CP];                   // 19584 B
    __shared__ float smst[2][64][2];                 // [wrow][c][s] : 1024 B

    int b  = blockIdx.z;
    int y0 = blockIdx.y * 2;
    int x0 = blockIdx.x * 32;
    int tid = threadIdx.x, lane = tid & 63, wave = tid >> 6;
    int ln2 = lane & 31, hi = lane >> 5, oh = wave & 1, wrow = wave >> 1;
    const short* hb = hin + (size_t)b*HWSZ*64;
    const short* cb = FUSEA ? (cin + (size_t)b*HWSZ*64) : nullptr;
    short* ab = WB ? (aout + (size_t)b*HWSZ*64) : nullptr;
    const float* stb = stin + b*64*2;

    // ---- bulk stage: 4 rows x 32 px x 64 c, 16B chunks, fully coalesced ----
    float mean[8], rstd[8];
    if (NORM || FUSEA) {
        int c0 = (tid & 7) * 8;                      // thread's c-octet is fixed (256%8==0)
#pragma unroll
        for (int j = 0; j < 8; ++j) {
            float s = stb[(c0+j)*2], s2 = stb[(c0+j)*2+1];
            float m = s * (1.f/HWSZ);
            float var = s2 * (1.f/HWSZ) - m*m;
            mean[j] = m; rstd[j] = rsqrtf(fmaxf(var, 0.f) + EPSV);
        }
    }
#pragma unroll
    for (int it = 0; it < 4; ++it) {
        int chunk = tid + it*256;                    // 1024 chunks
        int r = chunk >> 8, o = chunk & 255, px = o >> 3, oc = o & 7;
        int yy = refl(y0 - 1 + r, HH);
        size_t base = ((size_t)(yy*WW + x0 + px))*64 + oc*8;
        short8 v = *(const short8*)(hb + base);
        if (NORM) {
#pragma unroll
            for (int j = 0; j < 8; ++j) {
                float f = bf2f(v[j]);
                f = fmaxf((f - mean[j]) * rstd[j], 0.f);
                v[j] = f2bf(f);
            }
        }
        if (FUSEA) {
            short8 cv = *(const short8*)(cb + base);
#pragma unroll
            for (int j = 0; j < 8; ++j) {
                float f = bf2f(v[j]) + (bf2f(cv[j]) - mean[j]) * rstd[j];
                v[j] = f2bf(fmaxf(f, 0.f));
            }
        }
        *(short8*)(lds + (r*34 + 1 + px)*CP + oc*8) = v;
        if (WB) {
            if (r == 1 || r == 2) *(short8*)(ab + base) = v;   // own rows y0, y0+1 only
        }
    }
    // ---- halo columns x0-1 and x0+32 (x-reflected at edges) ----
    {
        int r = tid >> 6, c = tid & 63;
        int xm = (x0 == 0) ? 1 : x0 - 1;
        int xp = (x0 + 32 == WW) ? WW - 2 : x0 + 32;
        int yy = refl(y0 - 1 + r, HH);
        float fa = bf2f(hb[((size_t)(yy*WW + xm))*64 + c]);
        float fb = bf2f(hb[((size_t)(yy*WW + xp))*64 + c]);
        if (NORM || FUSEA) {
            float s = stb[c*2], s2 = stb[c*2+1];
            float m = s * (1.f/HWSZ);
            float rs = rsqrtf(fmaxf(s2*(1.f/HWSZ) - m*m, 0.f) + EPSV);
            if (NORM) {
                fa = fmaxf((fa - m)*rs, 0.f);
                fb = fmaxf((fb - m)*rs, 0.f);
            } else {
                float fca = bf2f(cb[((size_t)(yy*WW + xm))*64 + c]);
                float fcb = bf2f(cb[((size_t)(yy*WW + xp))*64 + c]);
                fa = fmaxf(fa + (fca - m)*rs, 0.f);
                fb = fmaxf(fb + (fcb - m)*rs, 0.f);
            }
        }
        lds[(r*34 + 0)*CP + c]  = f2bf(fa);
        lds[(r*34 + 33)*CP + c] = f2bf(fb);
    }
    __syncthreads();

    // ---- per-lane K values (pixel = x0+ln2, row = y0+wrow) ----
    float kv[9];
    if (HASK) {
#pragma unroll
        for (int t = 0; t < 9; ++t)
            kv[t] = Kb[((size_t)(b*9 + t))*HWSZ + (y0 + wrow)*WW + x0 + ln2];
    }

    floatx16 acc = (floatx16)(0.f);
    const short8* Ap8 = (const short8*)Ap;
#pragma unroll
    for (int t = 0; t < 9; ++t) {
        int dy = t/3 - 1, dx = t%3 - 1;
        int rr = wrow + dy + 1;                      // 0..3
        floatx16 tmp;
#pragma unroll
        for (int cg = 0; cg < 4; ++cg) {
            short8 bf = *(const short8*)(lds + (rr*34 + 1 + ln2 + dx)*CP + cg*16 + hi*8);
            short8 af = Ap8[((size_t)(t*4 + cg)*2 + oh)*64 + lane];
            if (HASK)
                tmp = __builtin_amdgcn_mfma_f32_32x32x16_bf16(af, bf, cg == 0 ? (floatx16)(0.f) : tmp, 0, 0, 0);
            else
                acc = __builtin_amdgcn_mfma_f32_32x32x16_bf16(af, bf, acc, 0, 0, 0);
        }
        if (HASK) {
#pragma unroll
            for (int r = 0; r < 16; ++r) acc[r] = fmaf(kv[t], tmp[r], acc[r]);
        }
    }

    // ---- epilogue: C/D col=lane&31 (px), row o = (reg&3)+8*(reg>>2)+4*hi+32*oh ----
    // fold bias into acc first (needed by both the store and the fused stats)
#pragma unroll
    for (int q = 0; q < 4; ++q) {
        int o0 = oh*32 + hi*4 + 8*q;
        float4 bq = *(const float4*)(bias + o0);
#pragma unroll
        for (int jj = 0; jj < 4; ++jj) acc[q*4 + jj] += ((float*)&bq)[jj];
    }

    if constexpr (STATS) {
        // per-(b,channel) sum / sumsq over this wave's 32 pixels, DPP tree over columns.
        // Block-level combine via LDS (each slot written exactly once), then ONE
        // 128-float partial record per block via agent-scope atomic stores.
        float s[16], s2[16];
#pragma unroll
        for (int r = 0; r < 16; ++r) { float v = acc[r]; s[r] = red_cols(v); s2[r] = red_cols(v*v); }
        if ((lane & 31) == 16) {                     // lanes 16 and 48 hold the half sums
#pragma unroll
            for (int r = 0; r < 16; ++r) {
                int o = oh*32 + hi*4 + 8*(r >> 2) + (r & 3);
                smst[wrow][o][0] = s[r];
                smst[wrow][o][1] = s2[r];
            }
        }
        __syncthreads();
        if (tid < 128) {
            int blk = blockIdx.y * gridDim.x + blockIdx.x;   // 0..1023
            float v = smst[0][tid >> 1][tid & 1] + smst[1][tid >> 1][tid & 1];
            __hip_atomic_store(&stpart[((size_t)b*1024 + blk)*128 + tid], v,
                               __ATOMIC_RELAXED, __HIP_MEMORY_SCOPE_AGENT);
        }
    }

    int y = y0 + wrow, x = x0 + ln2;
#pragma unroll
    for (int q = 0; q < 4; ++q) {
        int o0 = oh*32 + hi*4 + 8*q;                 // regs 4q..4q+3 -> o0..o0+3
        if (FINAL) {
#pragma unroll
            for (int jj = 0; jj < 4; ++jj) {
                float val = fmaxf(acc[q*4 + jj], 0.f);
                outf[((size_t)(b*64 + o0 + jj))*HWSZ + y*WW + x] = val;  // NCHW fp32
            }
        } else {
            short4v pk;
#pragma unroll
            for (int jj = 0; jj < 4; ++jj) pk[jj] = f2bf(acc[q*4 + jj]);
            *(short4v*)(outb + ((size_t)b*HWSZ + (size_t)(y*WW + x))*64 + o0) = pk;
        }
    }

    if constexpr (STATS) {
        // ---- in-kernel final reduction by the 1024th block of this b ----
        __syncthreads();                             // barrier drains vmcnt: records visible
        __shared__ int lastf;
        if (tid == 0) lastf = (atomicAdd(&cnt[b], 1) == 1023) ? 1 : 0;
        __syncthreads();
        if (lastf) {
            __shared__ float sred[2][128];
            int c2 = tid & 127, half = tid >> 7;     // 2 threads per channel-stat column
            const float* p = stpart + ((size_t)b*1024 + (size_t)half*512)*128 + c2;
            float a0=0.f, a1=0.f, a2=0.f, a3=0.f;
            for (int rec = 0; rec < 512; rec += 4) {
                a0 += __hip_atomic_load(p + (size_t)(rec+0)*128, __ATOMIC_RELAXED, __HIP_MEMORY_SCOPE_AGENT);
                a1 += __hip_atomic_load(p + (size_t)(rec+1)*128, __ATOMIC_RELAXED, __HIP_MEMORY_SCOPE_AGENT);
                a2 += __hip_atomic_load(p + (size_t)(rec+2)*128, __ATOMIC_RELAXED, __HIP_MEMORY_SCOPE_AGENT);
                a3 += __hip_atomic_load(p + (size_t)(rec+3)*128, __ATOMIC_RELAXED, __HIP_MEMORY_SCOPE_AGENT);
            }
            sred[half][c2] = (a0 + a1) + (a2 + a3);
            __syncthreads();
            if (tid < 128) stfin[(size_t)b*128 + tid] = sred[0][tid] + sred[1][tid];
        }
    }
}

// ---------------- A <- relu(A + (C-mean)*rstd), bf16 channels-last (fallback path) ----
__global__ void addnorm_relu(short* __restrict__ A, const short* __restrict__ C,
                             const float* __restrict__ st){
    int idx = blockIdx.x*256 + threadIdx.x;          // BN*HWSZ*8
    int oc = idx & 7;
    size_t pq = (size_t)(idx >> 3);
    int b = (int)(pq / HWSZ);
    size_t base = pq*64 + oc*8;
    short8 a = *(short8*)(A + base);
    short8 c = *(const short8*)(C + base);
#pragma unroll
    for (int j = 0; j < 8; ++j) {
        int cc = oc*8 + j;
        float s = st[(b*64+cc)*2], s2 = st[(b*64+cc)*2+1];
        float m = s * (1.f/HWSZ);
        float rs = rsqrtf(fmaxf(s2*(1.f/HWSZ) - m*m, 0.f) + EPSV);
        float f = bf2f(a[j]) + (bf2f(c[j]) - m)*rs;
        a[j] = f2bf(fmaxf(f, 0.f));
    }
    *(short8*)(A + base) = a;
}

extern "C" void kernel_launch(void* const* d_in, const int* in_sizes, int n_in,
                              void* d_out, int out_size, void* d_ws, size_t ws_size,
                              hipStream_t stream) {
    const float* x   = (const float*)d_in[0];
    // d_in[1] = grad_img: unused by the reference
    const float* w0  = (const float*)d_in[2];
    const float* b0  = (const float*)d_in[3];
    const float* wf  = (const float*)d_in[4];
    const float* bf  = (const float*)d_in[5];
    const float* w1a = (const float*)d_in[6];  const float* b1a = (const float*)d_in[7];
    const float* w1b = (const float*)d_in[8];  const float* b1b = (const float*)d_in[9];
    const float* w2a = (const float*)d_in[10]; const float* b2a = (const float*)d_in[11];
    const float* w2b = (const float*)d_in[12]; const float* b2b = (const float*)d_in[13];
    const float* w3a = (const float*)d_in[14]; const float* b3a = (const float*)d_in[15];
    const float* w3b = (const float*)d_in[16]; const float* b3b = (const float*)d_in[17];

    const size_t TEN = (size_t)BN*HWSZ*64;            // bf16 tensor elements (16.7M shorts)
    float* ws   = (float*)d_ws;
    float* Kb   = ws;                                 // 2,359,296 f (9.4 MB)
    short* A    = (short*)(Kb + (size_t)BN*9*HWSZ);   // 33.5 MB
    short* Bb   = A + TEN;                            // 33.5 MB
    short* Apk  = Bb + TEN;                           // 0.5 MB
    float* st   = (float*)(Apk + (size_t)7*36864 + 64); // 6*512 f
    float* part = st + 6*BN*64*2;                     // BN*1024*128 f (2 MB)
    int*   cnt  = (int*)(part + (size_t)BN*1024*128); // 32 ints (6 pacs x BN used)
    short* A2   = (short*)(cnt + 32);                 // fused-only: 33.5 MB
    short* Ccw  = A2 + TEN;                           // fused-only: 33.5 MB
    size_t need = (size_t)((char*)(Ccw + TEN) - (char*)d_ws);
    const int FUSED = (ws_size >= need);
    short* Cc = FUSED ? Ccw : (short*)d_out;          // fallback: C scratch in d_out

    gc_kernel<<<(BN*HWSZ)/256, 256, 0, stream>>>(x, w0, b0, Kb, A, cnt);
    pack_all<<<dim3(144, 7), 256, 0, stream>>>(w1a, w1b, w2a, w2b, w3a, w3b, wf, Apk);

    dim3 g(WW/32, HH/2, BN);                          // 8 x 128 x 4 = 4096 blocks
    const int eblk = BN*HWSZ*8/256;
    const float* biasA[3] = {b1a, b2a, b3a};
    const float* biasB[3] = {b1b, b2b, b3b};
    // fused ping-pong: A holds h before rb0; rb1 writes h1->A2; rb2 writes h2->A
    short* ain[3]  = {A, A, A2};
    short* awb[3]  = {nullptr, A2, A};

    float* stPrev = nullptr;
    for (int rb = 0; rb < 3; ++rb) {
        float* stB = st + (size_t)(2*rb)   * BN*64*2;
        float* stC = st + (size_t)(2*rb+1) * BN*64*2;
        if (FUSED && rb > 0) {
            // pac_a with fused residual addnorm: h := relu(ain + norm(Cc,stPrev)),
            // write-back h to awb, conv -> Bb, stats reduced in-kernel -> stB
            pac_mfma<0,1,1,1,0,1><<<g, 256, 0, stream>>>(ain[rb], Cc, Kb,
                Apk + (size_t)(2*rb)*36864, biasA[rb], stPrev, Bb, nullptr, awb[rb],
                part, stB, cnt + (2*rb)*BN);
        } else {
            // raw staging pac_a (rb0, or fallback path where A was updated by addnorm)
            pac_mfma<0,0,0,1,0,1><<<g, 256, 0, stream>>>(ain[FUSED ? rb : 0], nullptr, Kb,
                Apk + (size_t)(2*rb)*36864, biasA[rb], st /*unused*/, Bb, nullptr, nullptr,
                part, stB, cnt + (2*rb)*BN);
        }
        // pac_b: staging applies norm(Bb,stB)+relu, K-modulated, stats -> stC in-kernel
        pac_mfma<1,0,0,1,0,1><<<g, 256, 0, stream>>>(Bb, nullptr, Kb,
            Apk + (size_t)(2*rb+1)*36864, biasB[rb], stB, Cc, nullptr, nullptr,
            part, stC, cnt + (2*rb+1)*BN);
        if (!FUSED) {
            addnorm_relu<<<eblk, 256, 0, stream>>>(A, Cc, stC);
        }
        stPrev = stC;
    }

    // final: plain 3x3 conv (no K), bias+relu, fp32 NCHW to d_out.
    // Fused: input h3 = relu(A + norm(Cc,st5)) computed in staging (A holds h2 after rb2
    // write-back; Cc/st5 from rb2's pac_b). Fallback: A was updated by addnorm.
    if (FUSED) {
        pac_mfma<0,1,0,0,1,0><<<g, 256, 0, stream>>>(A, Cc, Kb,
            Apk + (size_t)6*36864, bf, stPrev, nullptr, (float*)d_out, nullptr,
            nullptr, nullptr, nullptr);
    } else {
        pac_mfma<0,0,0,0,1,0><<<g, 256, 0, stream>>>(A, nullptr, Kb,
            Apk + (size_t)6*36864, bf, st /*unused*/, nullptr, (float*)d_out, nullptr,
            nullptr, nullptr, nullptr);
    }
}

// Round 13
// 442.382 us; speedup vs baseline: 1.3083x; 1.3083x over previous
//
#include <hip/hip_runtime.h>
#include <hip/hip_bf16.h>
#include <math.h>

#define BN 4
#define CHN 64
#define HH 256
#define WW 256
#define HWSZ (HH*WW)
#define EPSV 1e-5f
#define CP 72   // LDS channel-dim pad in shorts: 144B row stride -> 16B-aligned b128, balanced banks

typedef __attribute__((ext_vector_type(8)))  short  short8;
typedef __attribute__((ext_vector_type(4)))  short  short4v;
typedef __attribute__((ext_vector_type(16))) float  floatx16;

__device__ __forceinline__ int refl(int i, int n){ if(i<0)i=-i; if(i>=n)i=2*n-2-i; return i; }
__device__ __forceinline__ short f2bf(float f){ __hip_bfloat16 h=__float2bfloat16(f); return __builtin_bit_cast(short,h); }
__device__ __forceinline__ float bf2f(short s){ unsigned u=((unsigned)(unsigned short)s)<<16; return __builtin_bit_cast(float,u); }

// DPP-based add of a cross-lane shifted copy (VALU pipe only, no LDS traffic)
template<int CTRL>
__device__ __forceinline__ float dpp_add(float x){
    int y = __builtin_amdgcn_update_dpp(0, __builtin_bit_cast(int, x), CTRL, 0xF, 0xF, true);
    return x + __builtin_bit_cast(float, y);
}
// Reduce over the 32 "column" lanes of each 32-half.
// After this, lanes 16 (for lanes 0-31) and 48 (for lanes 32-63) hold the half sums.
__device__ __forceinline__ float red_cols(float x){
    x = dpp_add<0xB1>(x);    // quad_perm [1,0,3,2]  : xor 1
    x = dpp_add<0x4E>(x);    // quad_perm [2,3,0,1]  : xor 2
    x = dpp_add<0x124>(x);   // row_ror:4
    x = dpp_add<0x128>(x);   // row_ror:8  -> every lane holds its 16-row sum
    x = dpp_add<0x142>(x);   // row_bcast15 -> rows 1,3 accumulate rows 0,2
    return x;
}

// ---------------- guide: K[b,t,y,x] = exp(-0.5*(g_shift - g)^2), fp32 ----------------
// (conv1x1 is fused into rb0's pac_a staging -- this kernel no longer writes A)
__global__ void guide_kernel(const float* __restrict__ x, float* __restrict__ Kb) {
    int idx = blockIdx.x * 256 + threadIdx.x;
    if (idx >= BN*HWSZ) return;
    int b = idx / HWSZ, p = idx - b*HWSZ;
    int y = p / WW, xx = p - y*WW;
    const float* g = x + (size_t)b*HWSZ;
    float gc = g[p];
#pragma unroll
    for (int t = 0; t < 9; ++t) {
        int yy  = refl(y + t/3 - 1, HH);
        int xx2 = refl(xx + t%3 - 1, WW);
        float d = g[yy*WW + xx2] - gc;
        Kb[((size_t)b*9 + t)*HWSZ + p] = __expf(-0.5f*d*d);
    }
}

// ---------------- pack all 7 weight tensors into 32x32x16 A-fragment order ----------------
// frag = (t*4+cg)*2+oh ; o = oh*32+(lane&31) ; c = cg*16+(lane>>5)*8+j
__global__ void pack_all(const float* w1,const float* w2,const float* w3,const float* w4,
                         const float* w5,const float* w6,const float* w7, short* __restrict__ Ap){
    const float* wsrc[7] = {w1,w2,w3,w4,w5,w6,w7};
    int layer = blockIdx.y;
    int tid = blockIdx.x*256 + threadIdx.x;          // 0..36863
    int j    = tid & 7;
    int lane = (tid >> 3) & 63;
    int frag = tid >> 9;                             // 0..71
    int oh = frag & 1, cg = (frag >> 1) & 3, t = frag >> 3;
    int o = oh*32 + (lane & 31);
    int c = cg*16 + (lane >> 5)*8 + j;
    Ap[(size_t)layer*36864 + tid] = f2bf(wsrc[layer][(o*CHN + c)*9 + t]);
}

// ---------------- reduce per-block stat partials: st[b][c2] = sum over 1024 blocks ----------------
// part layout: [b][blk(1024)][c2(128)]; grid (128, BN) x 256 threads
__global__ void __launch_bounds__(256) reduce_stats(const float* __restrict__ part,
                                                    float* __restrict__ st){
    int b = blockIdx.y, c2 = blockIdx.x;
    const float* p = part + ((size_t)b*1024)*128 + c2;
    int tid = threadIdx.x;
    float s = 0.f;
#pragma unroll
    for (int k = 0; k < 4; ++k) s += p[(size_t)(tid + 256*k)*128];
#pragma unroll
    for (int m = 1; m < 64; m <<= 1) s += __shfl_xor(s, m);
    __shared__ float sm[4];
    if ((tid & 63) == 0) sm[tid >> 6] = s;
    __syncthreads();
    if (tid == 0) st[(size_t)b*128 + c2] = sm[0] + sm[1] + sm[2] + sm[3];
}

// ---------------- PAC conv, implicit GEMM on mfma_32x32x16_bf16 ----------------
// Block: 64 o x (32 px x 2 rows), 256 threads (R2-PROVEN config: __launch_bounds__(256,4),
// 56 VGPR, zero scratch). HW VGPR tiers step at 64/128/256 (R8/R9: any launch-bounds
// >4 waves/EU forces the <=64 tier and spills this body -- do NOT raise).
// In-kernel stats reduction (R12) FAILED: agent-scope (L2-bypass) loads on the last
// block's tail are ~10x slower than a cached reduce_stats dispatch -- keep it separate.
// Wave(oh=w&1, wrow=w>>1): 32 o x 32 px.
// h halo (4 rows x 34 px x 64 c, bf16 channels-last) staged to LDS ONCE; taps read
// shifted windows. K applied per tap on the C-tile (col=lane&31 = pixel):
//   acc += K[t,px] * (W_t x h_shift)  -- B-frags are RAW h, no per-element modulate.
// CONV1=1: staging computes h0[c] = w0[c]*x + b0[c] directly from fp32 x (1 channel) --
//          the conv1x1 fused in; bitwise-identical math to the old gc path. Cuts the
//          40MB A read to a 4MB x read. WB writes h0 to A for rb1's residual.
// NORM=1:  staging applies (v-mean)*rstd,relu from stats of hin (fuses applyrelu).
// FUSEA=1: staging computes h := relu(hin + (cin-mean)*rstd) -- residual addnorm fused
//          (stats are of cin). WB=1 writes the block's own 2 interior rows of h back to
//          aout (each element written by exactly one block; readers in later dispatches).
// STATS=1: epilogue accumulates per-(b,channel) sum/sumsq of fp32 outputs (bias incl.,
//          pre-relu) via DPP column reduce; block partials combined in LDS (NO atomics)
//          and stored as one coalesced 512B record per block.
template<int CONV1, int NORM, int FUSEA, int WB, int HASK, int FINAL, int STATS>
__global__ void __launch_bounds__(256, 4) pac_mfma(
    const short* __restrict__ hin, const short* __restrict__ cin,
    const float* __restrict__ Kb,
    const short* __restrict__ Ap, const float* __restrict__ bias,
    const float* __restrict__ stin, short* __restrict__ outb, float* __restrict__ outf,
    short* __restrict__ aout, float* __restrict__ stout,
    const float* __restrict__ xin, const float* __restrict__ w0c,
    const float* __restrict__ b0c)
{
    __shared__ short lds[4*34*CP];                   // 19584 B
    __shared__ float smst[2][64][2];                 // [wrow][c][s] : 1024 B

    int b  = blockIdx.z;
    int y0 = blockIdx.y * 2;
    int x0 = blockIdx.x * 32;
    int tid = threadIdx.x, lane = tid & 63, wave = tid >> 6;
    int ln2 = lane & 31, hi = lane >> 5, oh = wave & 1, wrow = wave >> 1;
    const short* hb = hin + (size_t)b*HWSZ*64;
    const short* cb = FUSEA ? (cin + (size_t)b*HWSZ*64) : nullptr;
    short* ab = WB ? (aout + (size_t)b*HWSZ*64) : nullptr;
    const float* xb = CONV1 ? (xin + (size_t)b*HWSZ) : nullptr;
    const float* stb = stin + b*64*2;

    // ---- bulk stage: 4 rows x 32 px x 64 c, 16B chunks, fully coalesced ----
    float mean[8], rstd[8];                          // CONV1 reuses as w8/b8
    if (NORM || FUSEA) {
        int c0 = (tid & 7) * 8;                      // thread's c-octet is fixed (256%8==0)
#pragma unroll
        for (int j = 0; j < 8; ++j) {
            float s = stb[(c0+j)*2], s2 = stb[(c0+j)*2+1];
            float m = s * (1.f/HWSZ);
            float var = s2 * (1.f/HWSZ) - m*m;
            mean[j] = m; rstd[j] = rsqrtf(fmaxf(var, 0.f) + EPSV);
        }
    }
    if (CONV1) {
        int c0 = (tid & 7) * 8;
#pragma unroll
        for (int j = 0; j < 8; ++j) { mean[j] = w0c[c0+j]; rstd[j] = b0c[c0+j]; }
    }
#pragma unroll
    for (int it = 0; it < 4; ++it) {
        int chunk = tid + it*256;                    // 1024 chunks
        int r = chunk >> 8, o = chunk & 255, px = o >> 3, oc = o & 7;
        int yy = refl(y0 - 1 + r, HH);
        size_t base = ((size_t)(yy*WW + x0 + px))*64 + oc*8;
        short8 v;
        if (CONV1) {
            float xv = xb[yy*WW + x0 + px];
#pragma unroll
            for (int j = 0; j < 8; ++j) v[j] = f2bf(fmaf(mean[j], xv, rstd[j]));
        } else {
            v = *(const short8*)(hb + base);
            if (NORM) {
#pragma unroll
                for (int j = 0; j < 8; ++j) {
                    float f = bf2f(v[j]);
                    f = fmaxf((f - mean[j]) * rstd[j], 0.f);
                    v[j] = f2bf(f);
                }
            }
            if (FUSEA) {
                short8 cv = *(const short8*)(cb + base);
#pragma unroll
                for (int j = 0; j < 8; ++j) {
                    float f = bf2f(v[j]) + (bf2f(cv[j]) - mean[j]) * rstd[j];
                    v[j] = f2bf(fmaxf(f, 0.f));
                }
            }
        }
        *(short8*)(lds + (r*34 + 1 + px)*CP + oc*8) = v;
        if (WB) {
            if (r == 1 || r == 2) *(short8*)(ab + base) = v;   // own rows y0, y0+1 only
        }
    }
    // ---- halo columns x0-1 and x0+32 (x-reflected at edges) ----
    {
        int r = tid >> 6, c = tid & 63;
        int xm = (x0 == 0) ? 1 : x0 - 1;
        int xp = (x0 + 32 == WW) ? WW - 2 : x0 + 32;
        int yy = refl(y0 - 1 + r, HH);
        float fa, fb;
        if (CONV1) {
            float wv = w0c[c], bv = b0c[c];
            fa = fmaf(wv, xb[yy*WW + xm], bv);
            fb = fmaf(wv, xb[yy*WW + xp], bv);
        } else {
            fa = bf2f(hb[((size_t)(yy*WW + xm))*64 + c]);
            fb = bf2f(hb[((size_t)(yy*WW + xp))*64 + c]);
            if (NORM || FUSEA) {
                float s = stb[c*2], s2 = stb[c*2+1];
                float m = s * (1.f/HWSZ);
                float rs = rsqrtf(fmaxf(s2*(1.f/HWSZ) - m*m, 0.f) + EPSV);
                if (NORM) {
                    fa = fmaxf((fa - m)*rs, 0.f);
                    fb = fmaxf((fb - m)*rs, 0.f);
                } else {
                    float fca = bf2f(cb[((size_t)(yy*WW + xm))*64 + c]);
                    float fcb = bf2f(cb[((size_t)(yy*WW + xp))*64 + c]);
                    fa = fmaxf(fa + (fca - m)*rs, 0.f);
                    fb = fmaxf(fb + (fcb - m)*rs, 0.f);
                }
            }
        }
        lds[(r*34 + 0)*CP + c]  = f2bf(fa);
        lds[(r*34 + 33)*CP + c] = f2bf(fb);
    }
    __syncthreads();

    // ---- per-lane K values (pixel = x0+ln2, row = y0+wrow) ----
    float kv[9];
    if (HASK) {
#pragma unroll
        for (int t = 0; t < 9; ++t)
            kv[t] = Kb[((size_t)(b*9 + t))*HWSZ + (y0 + wrow)*WW + x0 + ln2];
    }

    floatx16 acc = (floatx16)(0.f);
    const short8* Ap8 = (const short8*)Ap;
#pragma unroll
    for (int t = 0; t < 9; ++t) {
        int dy = t/3 - 1, dx = t%3 - 1;
        int rr = wrow + dy + 1;                      // 0..3
        floatx16 tmp;
#pragma unroll
        for (int cg = 0; cg < 4; ++cg) {
            short8 bf = *(const short8*)(lds + (rr*34 + 1 + ln2 + dx)*CP + cg*16 + hi*8);
            short8 af = Ap8[((size_t)(t*4 + cg)*2 + oh)*64 + lane];
            if (HASK)
                tmp = __builtin_amdgcn_mfma_f32_32x32x16_bf16(af, bf, cg == 0 ? (floatx16)(0.f) : tmp, 0, 0, 0);
            else
                acc = __builtin_amdgcn_mfma_f32_32x32x16_bf16(af, bf, acc, 0, 0, 0);
        }
        if (HASK) {
#pragma unroll
            for (int r = 0; r < 16; ++r) acc[r] = fmaf(kv[t], tmp[r], acc[r]);
        }
    }

    // ---- epilogue: C/D col=lane&31 (px), row o = (reg&3)+8*(reg>>2)+4*hi+32*oh ----
    // fold bias into acc first (needed by both the store and the fused stats)
#pragma unroll
    for (int q = 0; q < 4; ++q) {
        int o0 = oh*32 + hi*4 + 8*q;
        float4 bq = *(const float4*)(bias + o0);
#pragma unroll
        for (int jj = 0; jj < 4; ++jj) acc[q*4 + jj] += ((float*)&bq)[jj];
    }

    if constexpr (STATS) {
        // per-(b,channel) sum / sumsq over this wave's 32 pixels, DPP tree over columns.
        // Block-level combine via LDS (each slot written exactly once), then ONE
        // coalesced 128-float partial record per block. No global atomics.
        float s[16], s2[16];
#pragma unroll
        for (int r = 0; r < 16; ++r) { float v = acc[r]; s[r] = red_cols(v); s2[r] = red_cols(v*v); }
        if ((lane & 31) == 16) {                     // lanes 16 and 48 hold the half sums
#pragma unroll
            for (int r = 0; r < 16; ++r) {
                int o = oh*32 + hi*4 + 8*(r >> 2) + (r & 3);
                smst[wrow][o][0] = s[r];
                smst[wrow][o][1] = s2[r];
            }
        }
        __syncthreads();
        if (tid < 128) {
            int blk = blockIdx.y * gridDim.x + blockIdx.x;   // 0..1023
            stout[((size_t)b*1024 + blk)*128 + tid] =
                smst[0][tid >> 1][tid & 1] + smst[1][tid >> 1][tid & 1];
        }
    }

    int y = y0 + wrow, x = x0 + ln2;
#pragma unroll
    for (int q = 0; q < 4; ++q) {
        int o0 = oh*32 + hi*4 + 8*q;                 // regs 4q..4q+3 -> o0..o0+3
        if (FINAL) {
#pragma unroll
            for (int jj = 0; jj < 4; ++jj) {
                float val = fmaxf(acc[q*4 + jj], 0.f);
                outf[((size_t)(b*64 + o0 + jj))*HWSZ + y*WW + x] = val;  // NCHW fp32
            }
        } else {
            short4v pk;
#pragma unroll
            for (int jj = 0; jj < 4; ++jj) pk[jj] = f2bf(acc[q*4 + jj]);
            *(short4v*)(outb + ((size_t)b*HWSZ + (size_t)(y*WW + x))*64 + o0) = pk;
        }
    }
}

// ---------------- A <- relu(A + (C-mean)*rstd), bf16 channels-last (fallback path) ----
__global__ void addnorm_relu(short* __restrict__ A, const short* __restrict__ C,
                             const float* __restrict__ st){
    int idx = blockIdx.x*256 + threadIdx.x;          // BN*HWSZ*8
    int oc = idx & 7;
    size_t pq = (size_t)(idx >> 3);
    int b = (int)(pq / HWSZ);
    size_t base = pq*64 + oc*8;
    short8 a = *(short8*)(A + base);
    short8 c = *(const short8*)(C + base);
#pragma unroll
    for (int j = 0; j < 8; ++j) {
        int cc = oc*8 + j;
        float s = st[(b*64+cc)*2], s2 = st[(b*64+cc)*2+1];
        float m = s * (1.f/HWSZ);
        float rs = rsqrtf(fmaxf(s2*(1.f/HWSZ) - m*m, 0.f) + EPSV);
        float f = bf2f(a[j]) + (bf2f(c[j]) - m)*rs;
        a[j] = f2bf(fmaxf(f, 0.f));
    }
    *(short8*)(A + base) = a;
}

extern "C" void kernel_launch(void* const* d_in, const int* in_sizes, int n_in,
                              void* d_out, int out_size, void* d_ws, size_t ws_size,
                              hipStream_t stream) {
    const float* x   = (const float*)d_in[0];
    // d_in[1] = grad_img: unused by the reference
    const float* w0  = (const float*)d_in[2];
    const float* b0  = (const float*)d_in[3];
    const float* wf  = (const float*)d_in[4];
    const float* bf  = (const float*)d_in[5];
    const float* w1a = (const float*)d_in[6];  const float* b1a = (const float*)d_in[7];
    const float* w1b = (const float*)d_in[8];  const float* b1b = (const float*)d_in[9];
    const float* w2a = (const float*)d_in[10]; const float* b2a = (const float*)d_in[11];
    const float* w2b = (const float*)d_in[12]; const float* b2b = (const float*)d_in[13];
    const float* w3a = (const float*)d_in[14]; const float* b3a = (const float*)d_in[15];
    const float* w3b = (const float*)d_in[16]; const float* b3b = (const float*)d_in[17];

    const size_t TEN = (size_t)BN*HWSZ*64;            // bf16 tensor elements (16.7M shorts)
    float* ws   = (float*)d_ws;
    float* Kb   = ws;                                 // 2,359,296 f (9.4 MB)
    short* A    = (short*)(Kb + (size_t)BN*9*HWSZ);   // 33.5 MB
    short* Bb   = A + TEN;                            // 33.5 MB
    short* Apk  = Bb + TEN;                           // 0.5 MB
    float* st   = (float*)(Apk + (size_t)7*36864 + 64); // 6*512 f
    float* part = st + 6*BN*64*2;                     // BN*1024*128 f (2 MB)
    short* A2   = (short*)(part + (size_t)BN*1024*128); // fused-only: 33.5 MB
    short* Ccw  = A2 + TEN;                           // fused-only: 33.5 MB
    size_t need = (size_t)((char*)(Ccw + TEN) - (char*)d_ws);
    const int FUSED = (ws_size >= need);
    short* Cc = FUSED ? Ccw : (short*)d_out;          // fallback: C scratch in d_out

    guide_kernel<<<(BN*HWSZ + 255)/256, 256, 0, stream>>>(x, Kb);
    pack_all<<<dim3(144, 7), 256, 0, stream>>>(w1a, w1b, w2a, w2b, w3a, w3b, wf, Apk);

    dim3 g(WW/32, HH/2, BN);                          // 8 x 128 x 4 = 4096 blocks
    dim3 gr(128, BN);                                 // reduce_stats grid
    const int eblk = BN*HWSZ*8/256;
    const float* biasA[3] = {b1a, b2a, b3a};
    const float* biasB[3] = {b1b, b2b, b3b};
    // fused ping-pong: rb0 CONV1 writes h0->A; rb1 reads A, writes h1->A2; rb2 reads A2,
    // writes h2->A; final reads A. Fallback: A updated in place by addnorm_relu.
    short* ain[3]  = {A, A, A2};
    short* awb[3]  = {A, A2, A};

    float* stPrev = nullptr;
    for (int rb = 0; rb < 3; ++rb) {
        float* stB = st + (size_t)(2*rb)   * BN*64*2;
        float* stC = st + (size_t)(2*rb+1) * BN*64*2;
        if (rb == 0) {
            // pac_a with fused conv1x1: staging computes h0 = w0*x+b0 from fp32 x,
            // write-back h0 -> A (both paths), conv -> Bb, stat partials -> part
            pac_mfma<1,0,0,1,1,0,1><<<g, 256, 0, stream>>>(A, nullptr, Kb,
                Apk, biasA[0], st /*unused*/, Bb, nullptr, A, part, x, w0, b0);
        } else if (FUSED) {
            // pac_a with fused residual addnorm: h := relu(ain + norm(Cc,stPrev)),
            // write-back h -> awb, conv -> Bb, stat partials -> part
            pac_mfma<0,0,1,1,1,0,1><<<g, 256, 0, stream>>>(ain[rb], Cc, Kb,
                Apk + (size_t)(2*rb)*36864, biasA[rb], stPrev, Bb, nullptr, awb[rb],
                part, nullptr, nullptr, nullptr);
        } else {
            // fallback: raw staging pac_a (A was updated in place by addnorm_relu)
            pac_mfma<0,0,0,0,1,0,1><<<g, 256, 0, stream>>>(A, nullptr, Kb,
                Apk + (size_t)(2*rb)*36864, biasA[rb], st /*unused*/, Bb, nullptr, nullptr,
                part, nullptr, nullptr, nullptr);
        }
        reduce_stats<<<gr, 256, 0, stream>>>(part, stB);
        // pac_b: staging applies norm(Bb,stB)+relu, K-modulated, bf16 out, partials -> part
        pac_mfma<0,1,0,0,1,0,1><<<g, 256, 0, stream>>>(Bb, nullptr, Kb,
            Apk + (size_t)(2*rb+1)*36864, biasB[rb], stB, Cc, nullptr, nullptr,
            part, nullptr, nullptr, nullptr);
        reduce_stats<<<gr, 256, 0, stream>>>(part, stC);
        if (!FUSED) {
            addnorm_relu<<<eblk, 256, 0, stream>>>(A, Cc, stC);
        }
        stPrev = stC;
    }

    // final: plain 3x3 conv (no K), bias+relu, fp32 NCHW to d_out.
    // Fused: input h3 = relu(A + norm(Cc,st5)) computed in staging (A holds h2 after rb2
    // write-back; Cc/st5 from rb2's pac_b). Fallback: A was updated by addnorm.
    if (FUSED) {
        pac_mfma<0,0,1,0,0,1,0><<<g, 256, 0, stream>>>(A, Cc, Kb,
            Apk + (size_t)6*36864, bf, stPrev, nullptr, (float*)d_out, nullptr,
            nullptr, nullptr, nullptr, nullptr);
    } else {
        pac_mfma<0,0,0,0,0,1,0><<<g, 256, 0, stream>>>(A, nullptr, Kb,
            Apk + (size_t)6*36864, bf, st /*unused*/, nullptr, (float*)d_out, nullptr,
            nullptr, nullptr, nullptr, nullptr);
    }
}